// Round 3
// baseline (627.587 us; speedup 1.0000x reference)
//
#include <hip/hip_runtime.h>
#include <hip/hip_bf16.h>
#include <cmath>

// ---- problem constants ----
constexpr int cB  = 2;
constexpr int cS  = 1024;
constexpr int cNH = 32;
constexpr int cHD = 128;
constexpr int cHID = 4096;
constexpr int cM  = cB * cS;        // 2048 rows

typedef unsigned short u16;
typedef __bf16 bf16x8 __attribute__((ext_vector_type(8)));
typedef float  f32x4  __attribute__((ext_vector_type(4)));

__device__ __forceinline__ u16 f2b(float f) { return __builtin_bit_cast(u16, (__bf16)f); }

// ---------------- f32 -> bf16, 8 elems/thread ----------------
__global__ void cvt_bf16(const float* __restrict__ in, u16* __restrict__ out, int n8) {
  int i = blockIdx.x * blockDim.x + threadIdx.x;
  if (i >= n8) return;
  const float4* in4 = (const float4*)in;
  float4 a = in4[2 * i], b = in4[2 * i + 1];
  union { u16 u[8]; uint4 v; } r;
  r.u[0] = f2b(a.x); r.u[1] = f2b(a.y); r.u[2] = f2b(a.z); r.u[3] = f2b(a.w);
  r.u[4] = f2b(b.x); r.u[5] = f2b(b.y); r.u[6] = f2b(b.z); r.u[7] = f2b(b.w);
  ((uint4*)out)[i] = r.v;
}

// ---------------- RoPE cos/sin table: [B*S][64] ----------------
__global__ void rope_table_k(const int* __restrict__ pos,
                             float* __restrict__ cosT, float* __restrict__ sinT) {
  int idx = blockIdx.x * blockDim.x + threadIdx.x;   // < B*S*64
  int i = idx & 63, bs = idx >> 6;
  float p = (float)pos[bs];
  float freq = exp2f(-(float)i * (13.287712379549449f / 64.0f));
  float a = p * freq;
  float s, c;
  sincosf(a, &s, &c);
  cosT[idx] = c; sinT[idx] = s;
}

// ---------------- RoPE in-place on Q and K (bf16), interleaved pairs ------
__global__ void rope_apply(u16* __restrict__ Q, u16* __restrict__ Kb,
                           const float* __restrict__ cosT, const float* __restrict__ sinT) {
  int idx = blockIdx.x * blockDim.x + threadIdx.x;
  const int nPer = cB * cS * cNH * (cHD / 8);        // 1,048,576
  u16* P = (idx < nPer) ? Q : Kb;
  int t = (idx < nPer) ? idx : idx - nPer;
  int d8 = t & 15;
  int h  = (t >> 4) & 31;
  int bs = t >> 9;
  size_t base = ((size_t)bs * cNH + h) * cHD + d8 * 8;
  uint4 v = *reinterpret_cast<uint4*>(P + base);
  u16* u = reinterpret_cast<u16*>(&v);
  int pb = bs * 64 + d8 * 4;
  float4 cs = *reinterpret_cast<const float4*>(cosT + pb);
  float4 sn = *reinterpret_cast<const float4*>(sinT + pb);
  float co[4] = {cs.x, cs.y, cs.z, cs.w};
  float si[4] = {sn.x, sn.y, sn.z, sn.w};
#pragma unroll
  for (int p = 0; p < 4; ++p) {
    float e = (float)__builtin_bit_cast(__bf16, u[2 * p]);
    float o = (float)__builtin_bit_cast(__bf16, u[2 * p + 1]);
    float e2 = e * co[p] - o * si[p];
    float o2 = o * co[p] + e * si[p];
    u[2 * p]     = f2b(e2);
    u[2 * p + 1] = f2b(o2);
  }
  *reinterpret_cast<uint4*>(P + base) = v;
}

// ---------------- V [B,S,NH,HD] -> Vt [B*NH, HD, S] ----------------
__global__ void transpose_v(const u16* __restrict__ V, u16* __restrict__ Vt) {
  __shared__ u16 tile[32][33];
  int bh = blockIdx.z;
  int b = bh >> 5, h = bh & 31;
  int s0 = blockIdx.x * 32, d0 = blockIdx.y * 32;
  int tx = threadIdx.x & 31, ty0 = threadIdx.x >> 5;
#pragma unroll
  for (int i = 0; i < 4; ++i) {
    int r = ty0 + i * 8;
    tile[r][tx] = V[((size_t)(b * cS + s0 + r) * cNH + h) * cHD + d0 + tx];
  }
  __syncthreads();
#pragma unroll
  for (int i = 0; i < 4; ++i) {
    int r = ty0 + i * 8;
    Vt[((size_t)bh * cHD + d0 + r) * cS + s0 + tx] = tile[tx][r];
  }
}

// ---------------- GEMM: C[M,Ntot] = A[M,K] @ [W0;W1;W2]^T (+bias) ---------
// m97 structure: 128x128 tile, 4 waves, BK=64, global_load_lds width-16,
// linear LDS. Block's n-tile picks weight matrix sel = gn0>>12 (each W is
// [4096][4096]). XCD-bijective swizzle (nwg%8==0 in all launch configs).
// MODE 0: bf16 out + bias (QKV). MODE 1: f32 out + bias (O direct).
// MODE 2: f32 partial, no bias, z-sliced split-K buffer.
template <int MODE>
__global__ __launch_bounds__(256)
void gemm_bt(const u16* __restrict__ A,
             const u16* __restrict__ W0, const u16* __restrict__ W1,
             const u16* __restrict__ W2,
             const float* __restrict__ b0, const float* __restrict__ b1,
             const float* __restrict__ b2,
             void* o0, void* o1, void* o2, int kLen) {
  __shared__ __align__(16) u16 sA[128 * 64];
  __shared__ __align__(16) u16 sB[128 * 64];
  const int tid = threadIdx.x;
  const int w = tid >> 6, lane = tid & 63;
  const int c = lane & 15, g = lane >> 4;
  // bijective XCD swizzle
  const int nwg = gridDim.x * gridDim.y;
  const int bid = blockIdx.y * gridDim.x + blockIdx.x;
  const int chunkSz = nwg >> 3;
  const int swz = (bid & 7) * chunkSz + (bid >> 3);
  const int m0 = (swz / gridDim.x) * 128;
  const int gn0 = (swz % gridDim.x) * 128;
  const int sel = gn0 >> 12;
  const int n0 = gn0 & 4095;
  const u16* Bw = (sel == 0) ? W0 : (sel == 1 ? W1 : W2);
  const int k0 = blockIdx.z * kLen;
  const int wm = w >> 1, wn = w & 1;

  f32x4 acc[4][4] = {};

  const int nkt = kLen >> 6;
  for (int kt = 0; kt < nkt; ++kt) {
#pragma unroll
    for (int j = 0; j < 4; ++j) {
      int chunk = (j * 4 + w) * 64 + lane;       // 0..1023
      int row = chunk >> 3, lc = chunk & 7;      // 8 chunks (128B) per row
      __builtin_amdgcn_global_load_lds(
          (const void*)(A + (size_t)(m0 + row) * cHID + k0 + kt * 64 + lc * 8),
          (void*)(sA + (size_t)(j * 4 + w) * 512), 16, 0, 0);
      __builtin_amdgcn_global_load_lds(
          (const void*)(Bw + (size_t)(n0 + row) * cHID + k0 + kt * 64 + lc * 8),
          (void*)(sB + (size_t)(j * 4 + w) * 512), 16, 0, 0);
    }
    __syncthreads();

    bf16x8 af[2][4], bfr[2][4];
#pragma unroll
    for (int kf = 0; kf < 2; ++kf) {
#pragma unroll
      for (int f = 0; f < 4; ++f) {
        int ra = wm * 64 + f * 16 + c;
        af[kf][f] = *reinterpret_cast<const bf16x8*>(sA + ra * 64 + (kf * 4 + g) * 8);
        int rb = wn * 64 + f * 16 + c;
        bfr[kf][f] = *reinterpret_cast<const bf16x8*>(sB + rb * 64 + (kf * 4 + g) * 8);
      }
    }
#pragma unroll
    for (int kf = 0; kf < 2; ++kf)
#pragma unroll
      for (int mf = 0; mf < 4; ++mf)
#pragma unroll
        for (int nf = 0; nf < 4; ++nf)
          acc[mf][nf] = __builtin_amdgcn_mfma_f32_16x16x32_bf16(af[kf][mf], bfr[kf][nf], acc[mf][nf], 0, 0, 0);
    __syncthreads();
  }

  const float* bp = (sel == 0) ? b0 : (sel == 1 ? b1 : b2);
  void* op = (sel == 0) ? o0 : (sel == 1 ? o1 : o2);
  float* fp = (float*)op;
  if (MODE == 2) fp += (size_t)blockIdx.z * cM * cHID;

#pragma unroll
  for (int nf = 0; nf < 4; ++nf) {
    int col = n0 + wn * 64 + nf * 16 + c;
    float bv = (MODE == 2) ? 0.f : bp[col];
#pragma unroll
    for (int mf = 0; mf < 4; ++mf) {
      int row = m0 + wm * 64 + mf * 16 + g * 4;
#pragma unroll
      for (int r = 0; r < 4; ++r) {
        float v = acc[mf][nf][r] + bv;
        if (MODE == 0)
          ((u16*)op)[(size_t)(row + r) * cHID + col] = f2b(v);
        else
          fp[(size_t)(row + r) * cHID + col] = v;
      }
    }
  }
}

// ---------------- split-K combine: out = P0 + P1 + bias ----------------
__global__ void combine_bias(const float* __restrict__ P,
                             const float* __restrict__ bias,
                             float* __restrict__ out) {
  int i = blockIdx.x * blockDim.x + threadIdx.x;   // over cM*cHID/4
  float4 a = ((const float4*)P)[i];
  float4 b = ((const float4*)P)[i + (cM * cHID / 4)];
  int col4 = (i & (cHID / 4 - 1)) * 4;
  float4 bb = *reinterpret_cast<const float4*>(bias + col4);
  float4 r;
  r.x = a.x + b.x + bb.x; r.y = a.y + b.y + bb.y;
  r.z = a.z + b.z + bb.z; r.w = a.w + b.w + bb.w;
  ((float4*)out)[i] = r;
}

// ---------------- flash attention (causal), paired q-tiles, 4 waves -------
__global__ __launch_bounds__(256, 2)
void attn_kernel(const u16* __restrict__ Q, const u16* __restrict__ Kb,
                 const u16* __restrict__ Vt, u16* __restrict__ O) {
  __shared__ __align__(16) char sK[2][16384];  // [64 k][128 d] swizzled
  __shared__ __align__(16) char sV[2][16384];  // [128 d][64 k] swizzled
  __shared__ __align__(16) char sP[8192];      // per-wave [16 q][64 k] swizzled
  const int tid = threadIdx.x, w = tid >> 6, lane = tid & 63;
  const int c = lane & 15, g = lane >> 4;
  const int bh = blockIdx.y;
  const int b = bh >> 5, h = bh & 31;
  const int NT = cS / 64;                       // 16
  const int qtA = blockIdx.x, qtB = NT - 1 - blockIdx.x;
  const float kSc = 0.12751744f;                // log2(e)/sqrt(128)

  bf16x8 qf[2][4];
#pragma unroll
  for (int s = 0; s < 2; ++s) {
    int q0s = (s ? qtA : qtB) * 64;
    size_t qrow = ((size_t)(b * cS + q0s + w * 16 + c) * cNH + h) * cHD;
#pragma unroll
    for (int df = 0; df < 4; ++df)
      qf[s][df] = *reinterpret_cast<const bf16x8*>(Q + qrow + df * 32 + g * 8);
  }

  f32x4 o[2][8] = {};
  float mx[2][4], ls[2][4];
#pragma unroll
  for (int s = 0; s < 2; ++s)
#pragma unroll
    for (int r = 0; r < 4; ++r) { mx[s][r] = -1e30f; ls[s][r] = 0.f; }

  uint4 kv[4], vv[4];
#define LOADT(t)                                                               \
  {                                                                            \
    _Pragma("unroll") for (int i = 0; i < 4; ++i) {                            \
      int cidx = i * 256 + tid;                                                \
      { int row = cidx >> 4, ch = cidx & 15;                                   \
        kv[i] = *reinterpret_cast<const uint4*>(                               \
            Kb + ((size_t)(b * cS + (t) * 64 + row) * cNH + h) * cHD + ch * 8); } \
      { int row = cidx >> 3, ch = cidx & 7;                                    \
        vv[i] = *reinterpret_cast<const uint4*>(                               \
            Vt + ((size_t)bh * cHD + row) * cS + (t) * 64 + ch * 8); }         \
    }                                                                          \
  }
#define WRITET(buf)                                                            \
  {                                                                            \
    _Pragma("unroll") for (int i = 0; i < 4; ++i) {                            \
      int cidx = i * 256 + tid;                                                \
      { int row = cidx >> 4, ch = cidx & 15;                                   \
        *reinterpret_cast<uint4*>(sK[buf] + row * 256 + ((ch ^ (row & 7)) * 16)) = kv[i]; } \
      { int row = cidx >> 3, ch = cidx & 7;                                    \
        *reinterpret_cast<uint4*>(sV[buf] + row * 128 + ((ch ^ (row & 7)) * 16)) = vv[i]; } \
    }                                                                          \
  }

  LOADT(0);
  WRITET(0);
  int cur = 0;

  for (int t = 0; t <= qtB; ++t) {
    __syncthreads();
    if (t < qtB) LOADT(t + 1);

#pragma unroll
    for (int s = 0; s < 2; ++s) {
      const int qt_s = s ? qtA : qtB;
      if (t > qt_s) continue;
      const int q0_s = qt_s * 64;

      f32x4 sc[4] = {};
#pragma unroll
      for (int df = 0; df < 4; ++df) {
        bf16x8 kb[4];
#pragma unroll
        for (int cf = 0; cf < 4; ++cf) {
          int kr = cf * 16 + c;
          kb[cf] = *reinterpret_cast<const bf16x8*>(sK[cur] + kr * 256 + (((df * 4 + g) ^ (kr & 7)) * 16));
        }
#pragma unroll
        for (int cf = 0; cf < 4; ++cf)
          sc[cf] = __builtin_amdgcn_mfma_f32_16x16x32_bf16(qf[s][df], kb[cf], sc[cf], 0, 0, 0);
      }

      if (t == qt_s) {
#pragma unroll
        for (int cf = 0; cf < 4; ++cf) {
          int kg = t * 64 + cf * 16 + c;
#pragma unroll
          for (int r = 0; r < 4; ++r) {
            int qg = q0_s + w * 16 + g * 4 + r;
            if (kg > qg) sc[cf][r] = -1e30f;
          }
        }
      }

      float alpha[4];
#pragma unroll
      for (int r = 0; r < 4; ++r) {
        float v = fmaxf(fmaxf(sc[0][r], sc[1][r]), fmaxf(sc[2][r], sc[3][r]));
        v = fmaxf(v, __shfl_xor(v, 1));
        v = fmaxf(v, __shfl_xor(v, 2));
        v = fmaxf(v, __shfl_xor(v, 4));
        v = fmaxf(v, __shfl_xor(v, 8));
        float mn = fmaxf(mx[s][r], v);
        alpha[r] = exp2f((mx[s][r] - mn) * kSc);
        mx[s][r] = mn;
      }
      float rs[4] = {0.f, 0.f, 0.f, 0.f};
#pragma unroll
      for (int cf = 0; cf < 4; ++cf)
#pragma unroll
        for (int r = 0; r < 4; ++r) {
          float p = exp2f((sc[cf][r] - mx[s][r]) * kSc);
          sc[cf][r] = p;
          rs[r] += p;
        }
#pragma unroll
      for (int r = 0; r < 4; ++r) {
        float v = rs[r];
        v += __shfl_xor(v, 1); v += __shfl_xor(v, 2);
        v += __shfl_xor(v, 4); v += __shfl_xor(v, 8);
        ls[s][r] = ls[s][r] * alpha[r] + v;
      }
#pragma unroll
      for (int nf = 0; nf < 8; ++nf)
#pragma unroll
        for (int r = 0; r < 4; ++r)
          o[s][nf][r] *= alpha[r];

      char* myP = sP + w * 2048;
#pragma unroll
      for (int cf = 0; cf < 4; ++cf) {
        int kcol = cf * 16 + c;
        int chunk = kcol >> 3, within = kcol & 7;
#pragma unroll
        for (int r = 0; r < 4; ++r) {
          int qr = g * 4 + r;
          *reinterpret_cast<u16*>(myP + qr * 128 + ((chunk ^ (qr & 7)) * 16) + within * 2) =
              f2b(sc[cf][r]);
        }
      }
      bf16x8 pa[2];
#pragma unroll
      for (int kf = 0; kf < 2; ++kf)
        pa[kf] = *reinterpret_cast<const bf16x8*>(myP + c * 128 + (((kf * 4 + g) ^ (c & 7)) * 16));

#pragma unroll
      for (int kf = 0; kf < 2; ++kf) {
#pragma unroll
        for (int nf = 0; nf < 8; ++nf) {
          int dr = nf * 16 + c;
          bf16x8 vb = *reinterpret_cast<const bf16x8*>(sV[cur] + dr * 128 + (((kf * 4 + g) ^ (dr & 7)) * 16));
          o[s][nf] = __builtin_amdgcn_mfma_f32_16x16x32_bf16(pa[kf], vb, o[s][nf], 0, 0, 0);
        }
      }
    }

    if (t < qtB) { WRITET(cur ^ 1); cur ^= 1; }
  }

  __syncthreads();
#pragma unroll
  for (int s = 0; s < 2; ++s) {
#pragma unroll
    for (int nf = 0; nf < 8; ++nf) {
#pragma unroll
      for (int r = 0; r < 4; ++r) {
        float v = o[s][nf][r] / ls[s][r];
        int qr = w * 16 + g * 4 + r;
        *reinterpret_cast<u16*>(sK[s] + qr * 256 + (nf * 16 + c) * 2) = f2b(v);
      }
    }
  }
  __syncthreads();
#pragma unroll
  for (int s = 0; s < 2; ++s) {
    int q0_s = (s ? qtA : qtB) * 64;
#pragma unroll
    for (int i = 0; i < 4; ++i) {
      int cidx = i * 256 + tid;
      int row = cidx >> 4, ch = cidx & 15;
      uint4 v = *reinterpret_cast<const uint4*>(sK[s] + row * 256 + ch * 16);
      *reinterpret_cast<uint4*>(O + ((size_t)(b * cS + q0_s + row) * cNH + h) * cHD + ch * 8) = v;
    }
  }
#undef LOADT
#undef WRITET
}

// ---------------- host ----------------
extern "C" void kernel_launch(void* const* d_in, const int* in_sizes, int n_in,
                              void* d_out, int out_size, void* d_ws, size_t ws_size,
                              hipStream_t stream) {
  const float* x  = (const float*)d_in[0];
  const float* Wq = (const float*)d_in[1];
  const float* bq = (const float*)d_in[2];
  const float* Wk = (const float*)d_in[3];
  const float* bk = (const float*)d_in[4];
  const float* Wv = (const float*)d_in[5];
  const float* bv = (const float*)d_in[6];
  const float* Wo = (const float*)d_in[7];
  const float* bo = (const float*)d_in[8];
  const int*  pos = (const int*)d_in[9];
  float* out = (float*)d_out;

  char* ws = (char*)d_ws;
  const size_t MB = 1u << 20;
  const int W8 = (cHID * cHID) / 8;     // 2,097,152
  const int X8 = (cM * cHID) / 8;       // 1,048,576
  const int R8 = cB * cS * cNH * (cHD / 8);

  if (ws_size >= 168 * MB) {
    // -------- fused path (168 MiB) --------
    u16* xb  = (u16*)(ws);                 // 0-16
    u16* Qb  = (u16*)(ws + 16 * MB);       // 16-32
    u16* Kb  = (u16*)(ws + 32 * MB);       // 32-48
    u16* Vb  = (u16*)(ws + 48 * MB);       // 48-64
    float* cosT = (float*)(ws + 64 * MB);  // 64-65
    float* sinT = cosT + cB * cS * 64;
    u16* WbQ = (u16*)(ws + 72 * MB);       // 72-104
    u16* WbK = (u16*)(ws + 104 * MB);      // 104-136
    u16* WbV = (u16*)(ws + 136 * MB);      // 136-168
    u16* Vt  = WbQ;                        // weights dead after QKV GEMM
    u16* Ab  = WbK;
    u16* WbO = WbV;
    float* P01 = (float*)(ws);             // 0-64: split-K partials (xb..Vb dead)

    cvt_bf16<<<X8 / 256, 256, 0, stream>>>(x, xb, X8);
    cvt_bf16<<<W8 / 256, 256, 0, stream>>>(Wq, WbQ, W8);
    cvt_bf16<<<W8 / 256, 256, 0, stream>>>(Wk, WbK, W8);
    cvt_bf16<<<W8 / 256, 256, 0, stream>>>(Wv, WbV, W8);
    rope_table_k<<<(cB * cS * 64) / 256, 256, 0, stream>>>(pos, cosT, sinT);

    gemm_bt<0><<<dim3(96, 16), 256, 0, stream>>>(
        xb, WbQ, WbK, WbV, bq, bk, bv, Qb, Kb, Vb, cHID);

    rope_apply<<<(2 * R8) / 256, 256, 0, stream>>>(Qb, Kb, cosT, sinT);
    transpose_v<<<dim3(cS / 32, cHD / 32, cB * cNH), 256, 0, stream>>>(Vb, Vt);
    attn_kernel<<<dim3(cS / 128, cB * cNH), 256, 0, stream>>>(Qb, Kb, Vt, Ab);

    cvt_bf16<<<W8 / 256, 256, 0, stream>>>(Wo, WbO, W8);
    gemm_bt<2><<<dim3(32, 16, 2), 256, 0, stream>>>(
        Ab, WbO, WbO, WbO, nullptr, nullptr, nullptr, P01, P01, P01, cHID / 2);
    combine_bias<<<(cM * cHID / 4) / 256, 256, 0, stream>>>(P01, bo, out);
  } else {
    // -------- fallback serial path (97 MiB, round-2-proven) --------
    u16* xb = (u16*)(ws);                 // 0-16, later Vt
    u16* Wb = (u16*)(ws + 16 * MB);       // 16-48
    u16* Qb = (u16*)(ws + 48 * MB);       // 48-64
    u16* Kb = (u16*)(ws + 64 * MB);       // 64-80
    u16* Vb = (u16*)(ws + 80 * MB);       // 80-96, later attn out
    u16* Vt = xb;
    u16* Ab = Vb;
    float* cosT = (float*)(ws + 96 * MB);
    float* sinT = cosT + cB * cS * 64;

    cvt_bf16<<<X8 / 256, 256, 0, stream>>>(x, xb, X8);
    cvt_bf16<<<W8 / 256, 256, 0, stream>>>(Wq, Wb, W8);
    gemm_bt<0><<<dim3(32, 16), 256, 0, stream>>>(
        xb, Wb, Wb, Wb, bq, bq, bq, Qb, Qb, Qb, cHID);
    cvt_bf16<<<W8 / 256, 256, 0, stream>>>(Wk, Wb, W8);
    gemm_bt<0><<<dim3(32, 16), 256, 0, stream>>>(
        xb, Wb, Wb, Wb, bk, bk, bk, Kb, Kb, Kb, cHID);
    cvt_bf16<<<W8 / 256, 256, 0, stream>>>(Wv, Wb, W8);
    gemm_bt<0><<<dim3(32, 16), 256, 0, stream>>>(
        xb, Wb, Wb, Wb, bv, bv, bv, Vb, Vb, Vb, cHID);

    rope_table_k<<<(cB * cS * 64) / 256, 256, 0, stream>>>(pos, cosT, sinT);
    rope_apply<<<(2 * R8) / 256, 256, 0, stream>>>(Qb, Kb, cosT, sinT);
    transpose_v<<<dim3(cS / 32, cHD / 32, cB * cNH), 256, 0, stream>>>(Vb, Vt);
    attn_kernel<<<dim3(cS / 128, cB * cNH), 256, 0, stream>>>(Qb, Kb, Vt, Ab);

    cvt_bf16<<<W8 / 256, 256, 0, stream>>>(Wo, Wb, W8);
    gemm_bt<1><<<dim3(32, 16), 256, 0, stream>>>(
        Ab, Wb, Wb, Wb, bo, bo, bo, out, out, out, cHID);
  }
}

// Round 4
// 550.411 us; speedup vs baseline: 1.1402x; 1.1402x over previous
//
#include <hip/hip_runtime.h>
#include <hip/hip_bf16.h>
#include <cmath>

// ---- problem constants ----
constexpr int cB  = 2;
constexpr int cS  = 1024;
constexpr int cNH = 32;
constexpr int cHD = 128;
constexpr int cHID = 4096;
constexpr int cM  = cB * cS;        // 2048 rows

typedef unsigned short u16;
typedef __bf16 bf16x8 __attribute__((ext_vector_type(8)));
typedef float  f32x4  __attribute__((ext_vector_type(4)));

__device__ __forceinline__ u16 f2b(float f) { return __builtin_bit_cast(u16, (__bf16)f); }

// ---------------- f32 -> bf16, 8 elems/thread ----------------
__global__ void cvt_bf16(const float* __restrict__ in, u16* __restrict__ out, int n8) {
  int i = blockIdx.x * blockDim.x + threadIdx.x;
  if (i >= n8) return;
  const float4* in4 = (const float4*)in;
  float4 a = in4[2 * i], b = in4[2 * i + 1];
  union { u16 u[8]; uint4 v; } r;
  r.u[0] = f2b(a.x); r.u[1] = f2b(a.y); r.u[2] = f2b(a.z); r.u[3] = f2b(a.w);
  r.u[4] = f2b(b.x); r.u[5] = f2b(b.y); r.u[6] = f2b(b.z); r.u[7] = f2b(b.w);
  ((uint4*)out)[i] = r.v;
}

// ---------------- RoPE cos/sin table: [B*S][64] ----------------
__global__ void rope_table_k(const int* __restrict__ pos,
                             float* __restrict__ cosT, float* __restrict__ sinT) {
  int idx = blockIdx.x * blockDim.x + threadIdx.x;   // < B*S*64
  int i = idx & 63, bs = idx >> 6;
  float p = (float)pos[bs];
  float freq = exp2f(-(float)i * (13.287712379549449f / 64.0f));
  float a = p * freq;
  float s, c;
  sincosf(a, &s, &c);
  cosT[idx] = c; sinT[idx] = s;
}

// ---------------- RoPE in-place on Q and K (bf16), interleaved pairs ------
__global__ void rope_apply(u16* __restrict__ Q, u16* __restrict__ Kb,
                           const float* __restrict__ cosT, const float* __restrict__ sinT) {
  int idx = blockIdx.x * blockDim.x + threadIdx.x;
  const int nPer = cB * cS * cNH * (cHD / 8);        // 1,048,576
  u16* P = (idx < nPer) ? Q : Kb;
  int t = (idx < nPer) ? idx : idx - nPer;
  int d8 = t & 15;
  int h  = (t >> 4) & 31;
  int bs = t >> 9;
  size_t base = ((size_t)bs * cNH + h) * cHD + d8 * 8;
  uint4 v = *reinterpret_cast<uint4*>(P + base);
  u16* u = reinterpret_cast<u16*>(&v);
  int pb = bs * 64 + d8 * 4;
  float4 cs = *reinterpret_cast<const float4*>(cosT + pb);
  float4 sn = *reinterpret_cast<const float4*>(sinT + pb);
  float co[4] = {cs.x, cs.y, cs.z, cs.w};
  float si[4] = {sn.x, sn.y, sn.z, sn.w};
#pragma unroll
  for (int p = 0; p < 4; ++p) {
    float e = (float)__builtin_bit_cast(__bf16, u[2 * p]);
    float o = (float)__builtin_bit_cast(__bf16, u[2 * p + 1]);
    float e2 = e * co[p] - o * si[p];
    float o2 = o * co[p] + e * si[p];
    u[2 * p]     = f2b(e2);
    u[2 * p + 1] = f2b(o2);
  }
  *reinterpret_cast<uint4*>(P + base) = v;
}

// ---------------- V [B,S,NH,HD] -> Vt [B*NH, HD, S] ----------------
__global__ void transpose_v(const u16* __restrict__ V, u16* __restrict__ Vt) {
  __shared__ u16 tile[32][33];
  int bh = blockIdx.z;
  int b = bh >> 5, h = bh & 31;
  int s0 = blockIdx.x * 32, d0 = blockIdx.y * 32;
  int tx = threadIdx.x & 31, ty0 = threadIdx.x >> 5;
#pragma unroll
  for (int i = 0; i < 4; ++i) {
    int r = ty0 + i * 8;
    tile[r][tx] = V[((size_t)(b * cS + s0 + r) * cNH + h) * cHD + d0 + tx];
  }
  __syncthreads();
#pragma unroll
  for (int i = 0; i < 4; ++i) {
    int r = ty0 + i * 8;
    Vt[((size_t)bh * cHD + d0 + r) * cS + s0 + tx] = tile[tx][r];
  }
}

// ---------------- GEMM: C[M,Ntot] = A[M,K] @ [W0;W1;W2]^T (+bias) ---------
// 128x128 tile, 4 waves, BK=64, global_load_lds width-16, linear LDS,
// minimal 2-phase double-buffer (T3): issue STAGE(kt+1, buf^1) BEFORE
// ds_read+MFMA of kt; one __syncthreads per K-step (its vmcnt(0) drain is
// overlapped by the compute). Race-free: STAGE targets the buffer whose
// reads completed before the PREVIOUS barrier.
// Grid: x = m-tile (consecutive blocks share the same weight panel -> L2/L3
// reuse; weights streamed ~once from HBM), y = n-tile, z = split-K slice.
// MODE 0: bf16 out + bias (QKV, y spans 3 weights). MODE 1: f32 out + bias.
// MODE 2: f32 partial, no bias, z-sliced split-K buffer.
template <int MODE>
__global__ __launch_bounds__(256)
void gemm_bt(const u16* __restrict__ A,
             const u16* __restrict__ W0, const u16* __restrict__ W1,
             const u16* __restrict__ W2,
             const float* __restrict__ b0, const float* __restrict__ b1,
             const float* __restrict__ b2,
             void* o0, void* o1, void* o2, int kLen) {
  __shared__ __align__(16) u16 sA[2][128 * 64];
  __shared__ __align__(16) u16 sB[2][128 * 64];
  const int tid = threadIdx.x;
  const int w = tid >> 6, lane = tid & 63;
  const int c = lane & 15, g = lane >> 4;
  const int m0 = blockIdx.x * 128;
  const int gn0 = blockIdx.y * 128;
  const int sel = gn0 >> 12;
  const int n0 = gn0 & 4095;
  const u16* Bw = (sel == 0) ? W0 : (sel == 1 ? W1 : W2);
  const int k0 = blockIdx.z * kLen;
  const int wm = w >> 1, wn = w & 1;

  f32x4 acc[4][4] = {};
  const int nkt = kLen >> 6;

#define STAGE(kt, buf)                                                         \
  {                                                                            \
    _Pragma("unroll") for (int j = 0; j < 4; ++j) {                            \
      int chunk = (j * 4 + w) * 64 + lane;                                     \
      int row = chunk >> 3, lc = chunk & 7;                                    \
      __builtin_amdgcn_global_load_lds(                                        \
          (const void*)(A + (size_t)(m0 + row) * cHID + k0 + (kt) * 64 + lc * 8), \
          (void*)(sA[buf] + (size_t)(j * 4 + w) * 512), 16, 0, 0);             \
      __builtin_amdgcn_global_load_lds(                                        \
          (const void*)(Bw + (size_t)(n0 + row) * cHID + k0 + (kt) * 64 + lc * 8), \
          (void*)(sB[buf] + (size_t)(j * 4 + w) * 512), 16, 0, 0);             \
    }                                                                          \
  }

  STAGE(0, 0);
  __syncthreads();                       // drains vmcnt(0): tile 0 resident

  for (int kt = 0; kt < nkt; ++kt) {
    const int buf = kt & 1;
    if (kt + 1 < nkt) STAGE(kt + 1, buf ^ 1);   // loads fly under compute

    bf16x8 af[2][4], bfr[2][4];
#pragma unroll
    for (int kf = 0; kf < 2; ++kf) {
#pragma unroll
      for (int f = 0; f < 4; ++f) {
        int ra = wm * 64 + f * 16 + c;
        af[kf][f] = *reinterpret_cast<const bf16x8*>(sA[buf] + ra * 64 + (kf * 4 + g) * 8);
        int rb = wn * 64 + f * 16 + c;
        bfr[kf][f] = *reinterpret_cast<const bf16x8*>(sB[buf] + rb * 64 + (kf * 4 + g) * 8);
      }
    }
#pragma unroll
    for (int kf = 0; kf < 2; ++kf)
#pragma unroll
      for (int mf = 0; mf < 4; ++mf)
#pragma unroll
        for (int nf = 0; nf < 4; ++nf)
          acc[mf][nf] = __builtin_amdgcn_mfma_f32_16x16x32_bf16(af[kf][mf], bfr[kf][nf], acc[mf][nf], 0, 0, 0);

    __syncthreads();   // vmcnt(0)+lgkmcnt(0)+barrier: next tile resident,
                       // and this tile's reads done before next STAGE overwrites
  }
#undef STAGE

  const float* bp = (sel == 0) ? b0 : (sel == 1 ? b1 : b2);
  void* op = (sel == 0) ? o0 : (sel == 1 ? o1 : o2);
  float* fp = (float*)op;
  if (MODE == 2) fp += (size_t)blockIdx.z * cM * cHID;

#pragma unroll
  for (int nf = 0; nf < 4; ++nf) {
    int col = n0 + wn * 64 + nf * 16 + c;
    float bv = (MODE == 2) ? 0.f : bp[col];
#pragma unroll
    for (int mf = 0; mf < 4; ++mf) {
      int row = m0 + wm * 64 + mf * 16 + g * 4;
#pragma unroll
      for (int r = 0; r < 4; ++r) {
        float v = acc[mf][nf][r] + bv;
        if (MODE == 0)
          ((u16*)op)[(size_t)(row + r) * cHID + col] = f2b(v);
        else
          fp[(size_t)(row + r) * cHID + col] = v;
      }
    }
  }
}

// ---------------- split-K combine: out = P0 + P1 + bias ----------------
__global__ void combine_bias(const float* __restrict__ P,
                             const float* __restrict__ bias,
                             float* __restrict__ out) {
  int i = blockIdx.x * blockDim.x + threadIdx.x;   // over cM*cHID/4
  float4 a = ((const float4*)P)[i];
  float4 b = ((const float4*)P)[i + (cM * cHID / 4)];
  int col4 = (i & (cHID / 4 - 1)) * 4;
  float4 bb = *reinterpret_cast<const float4*>(bias + col4);
  float4 r;
  r.x = a.x + b.x + bb.x; r.y = a.y + b.y + bb.y;
  r.z = a.z + b.z + bb.z; r.w = a.w + b.w + bb.w;
  ((float4*)out)[i] = r;
}

// ---------------- flash attention (causal), paired q-tiles, 4 waves -------
__global__ __launch_bounds__(256, 2)
void attn_kernel(const u16* __restrict__ Q, const u16* __restrict__ Kb,
                 const u16* __restrict__ Vt, u16* __restrict__ O) {
  __shared__ __align__(16) char sK[2][16384];  // [64 k][128 d] swizzled
  __shared__ __align__(16) char sV[2][16384];  // [128 d][64 k] swizzled
  __shared__ __align__(16) char sP[8192];      // per-wave [16 q][64 k] swizzled
  const int tid = threadIdx.x, w = tid >> 6, lane = tid & 63;
  const int c = lane & 15, g = lane >> 4;
  const int bh = blockIdx.y;
  const int b = bh >> 5, h = bh & 31;
  const int NT = cS / 64;                       // 16
  const int qtA = blockIdx.x, qtB = NT - 1 - blockIdx.x;
  const float kSc = 0.12751744f;                // log2(e)/sqrt(128)

  bf16x8 qf[2][4];
#pragma unroll
  for (int s = 0; s < 2; ++s) {
    int q0s = (s ? qtA : qtB) * 64;
    size_t qrow = ((size_t)(b * cS + q0s + w * 16 + c) * cNH + h) * cHD;
#pragma unroll
    for (int df = 0; df < 4; ++df)
      qf[s][df] = *reinterpret_cast<const bf16x8*>(Q + qrow + df * 32 + g * 8);
  }

  f32x4 o[2][8] = {};
  float mx[2][4], ls[2][4];
#pragma unroll
  for (int s = 0; s < 2; ++s)
#pragma unroll
    for (int r = 0; r < 4; ++r) { mx[s][r] = -1e30f; ls[s][r] = 0.f; }

  uint4 kv[4], vv[4];
#define LOADT(t)                                                               \
  {                                                                            \
    _Pragma("unroll") for (int i = 0; i < 4; ++i) {                            \
      int cidx = i * 256 + tid;                                                \
      { int row = cidx >> 4, ch = cidx & 15;                                   \
        kv[i] = *reinterpret_cast<const uint4*>(                               \
            Kb + ((size_t)(b * cS + (t) * 64 + row) * cNH + h) * cHD + ch * 8); } \
      { int row = cidx >> 3, ch = cidx & 7;                                    \
        vv[i] = *reinterpret_cast<const uint4*>(                               \
            Vt + ((size_t)bh * cHD + row) * cS + (t) * 64 + ch * 8); }         \
    }                                                                          \
  }
#define WRITET(buf)                                                            \
  {                                                                            \
    _Pragma("unroll") for (int i = 0; i < 4; ++i) {                            \
      int cidx = i * 256 + tid;                                                \
      { int row = cidx >> 4, ch = cidx & 15;                                   \
        *reinterpret_cast<uint4*>(sK[buf] + row * 256 + ((ch ^ (row & 7)) * 16)) = kv[i]; } \
      { int row = cidx >> 3, ch = cidx & 7;                                    \
        *reinterpret_cast<uint4*>(sV[buf] + row * 128 + ((ch ^ (row & 7)) * 16)) = vv[i]; } \
    }                                                                          \
  }

  LOADT(0);
  WRITET(0);
  int cur = 0;

  for (int t = 0; t <= qtB; ++t) {
    __syncthreads();
    if (t < qtB) LOADT(t + 1);

#pragma unroll
    for (int s = 0; s < 2; ++s) {
      const int qt_s = s ? qtA : qtB;
      if (t > qt_s) continue;
      const int q0_s = qt_s * 64;

      f32x4 sc[4] = {};
#pragma unroll
      for (int df = 0; df < 4; ++df) {
        bf16x8 kb[4];
#pragma unroll
        for (int cf = 0; cf < 4; ++cf) {
          int kr = cf * 16 + c;
          kb[cf] = *reinterpret_cast<const bf16x8*>(sK[cur] + kr * 256 + (((df * 4 + g) ^ (kr & 7)) * 16));
        }
#pragma unroll
        for (int cf = 0; cf < 4; ++cf)
          sc[cf] = __builtin_amdgcn_mfma_f32_16x16x32_bf16(qf[s][df], kb[cf], sc[cf], 0, 0, 0);
      }

      if (t == qt_s) {
#pragma unroll
        for (int cf = 0; cf < 4; ++cf) {
          int kg = t * 64 + cf * 16 + c;
#pragma unroll
          for (int r = 0; r < 4; ++r) {
            int qg = q0_s + w * 16 + g * 4 + r;
            if (kg > qg) sc[cf][r] = -1e30f;
          }
        }
      }

      float alpha[4];
#pragma unroll
      for (int r = 0; r < 4; ++r) {
        float v = fmaxf(fmaxf(sc[0][r], sc[1][r]), fmaxf(sc[2][r], sc[3][r]));
        v = fmaxf(v, __shfl_xor(v, 1));
        v = fmaxf(v, __shfl_xor(v, 2));
        v = fmaxf(v, __shfl_xor(v, 4));
        v = fmaxf(v, __shfl_xor(v, 8));
        float mn = fmaxf(mx[s][r], v);
        alpha[r] = exp2f((mx[s][r] - mn) * kSc);
        mx[s][r] = mn;
      }
      float rs[4] = {0.f, 0.f, 0.f, 0.f};
#pragma unroll
      for (int cf = 0; cf < 4; ++cf)
#pragma unroll
        for (int r = 0; r < 4; ++r) {
          float p = exp2f((sc[cf][r] - mx[s][r]) * kSc);
          sc[cf][r] = p;
          rs[r] += p;
        }
#pragma unroll
      for (int r = 0; r < 4; ++r) {
        float v = rs[r];
        v += __shfl_xor(v, 1); v += __shfl_xor(v, 2);
        v += __shfl_xor(v, 4); v += __shfl_xor(v, 8);
        ls[s][r] = ls[s][r] * alpha[r] + v;
      }
#pragma unroll
      for (int nf = 0; nf < 8; ++nf)
#pragma unroll
        for (int r = 0; r < 4; ++r)
          o[s][nf][r] *= alpha[r];

      char* myP = sP + w * 2048;
#pragma unroll
      for (int cf = 0; cf < 4; ++cf) {
        int kcol = cf * 16 + c;
        int chunk = kcol >> 3, within = kcol & 7;
#pragma unroll
        for (int r = 0; r < 4; ++r) {
          int qr = g * 4 + r;
          *reinterpret_cast<u16*>(myP + qr * 128 + ((chunk ^ (qr & 7)) * 16) + within * 2) =
              f2b(sc[cf][r]);
        }
      }
      bf16x8 pa[2];
#pragma unroll
      for (int kf = 0; kf < 2; ++kf)
        pa[kf] = *reinterpret_cast<const bf16x8*>(myP + c * 128 + (((kf * 4 + g) ^ (c & 7)) * 16));

#pragma unroll
      for (int kf = 0; kf < 2; ++kf) {
#pragma unroll
        for (int nf = 0; nf < 8; ++nf) {
          int dr = nf * 16 + c;
          bf16x8 vb = *reinterpret_cast<const bf16x8*>(sV[cur] + dr * 128 + (((kf * 4 + g) ^ (dr & 7)) * 16));
          o[s][nf] = __builtin_amdgcn_mfma_f32_16x16x32_bf16(pa[kf], vb, o[s][nf], 0, 0, 0);
        }
      }
    }

    if (t < qtB) { WRITET(cur ^ 1); cur ^= 1; }
  }

  __syncthreads();
#pragma unroll
  for (int s = 0; s < 2; ++s) {
#pragma unroll
    for (int nf = 0; nf < 8; ++nf) {
#pragma unroll
      for (int r = 0; r < 4; ++r) {
        float v = o[s][nf][r] / ls[s][r];
        int qr = w * 16 + g * 4 + r;
        *reinterpret_cast<u16*>(sK[s] + qr * 256 + (nf * 16 + c) * 2) = f2b(v);
      }
    }
  }
  __syncthreads();
#pragma unroll
  for (int s = 0; s < 2; ++s) {
    int q0_s = (s ? qtA : qtB) * 64;
#pragma unroll
    for (int i = 0; i < 4; ++i) {
      int cidx = i * 256 + tid;
      int row = cidx >> 4, ch = cidx & 15;
      uint4 v = *reinterpret_cast<const uint4*>(sK[s] + row * 256 + ch * 16);
      *reinterpret_cast<uint4*>(O + ((size_t)(b * cS + q0_s + row) * cNH + h) * cHD + ch * 8) = v;
    }
  }
#undef LOADT
#undef WRITET
}

// ---------------- host ----------------
extern "C" void kernel_launch(void* const* d_in, const int* in_sizes, int n_in,
                              void* d_out, int out_size, void* d_ws, size_t ws_size,
                              hipStream_t stream) {
  const float* x  = (const float*)d_in[0];
  const float* Wq = (const float*)d_in[1];
  const float* bq = (const float*)d_in[2];
  const float* Wk = (const float*)d_in[3];
  const float* bk = (const float*)d_in[4];
  const float* Wv = (const float*)d_in[5];
  const float* bv = (const float*)d_in[6];
  const float* Wo = (const float*)d_in[7];
  const float* bo = (const float*)d_in[8];
  const int*  pos = (const int*)d_in[9];
  float* out = (float*)d_out;

  char* ws = (char*)d_ws;
  const size_t MB = 1u << 20;
  const int W8 = (cHID * cHID) / 8;     // 2,097,152
  const int X8 = (cM * cHID) / 8;       // 1,048,576
  const int R8 = cB * cS * cNH * (cHD / 8);

  if (ws_size >= 168 * MB) {
    // -------- fused path (168 MiB) --------
    u16* xb  = (u16*)(ws);                 // 0-16
    u16* Qb  = (u16*)(ws + 16 * MB);       // 16-32
    u16* Kb  = (u16*)(ws + 32 * MB);       // 32-48
    u16* Vb  = (u16*)(ws + 48 * MB);       // 48-64
    float* cosT = (float*)(ws + 64 * MB);  // 64-65
    float* sinT = cosT + cB * cS * 64;
    u16* WbQ = (u16*)(ws + 72 * MB);       // 72-104
    u16* WbK = (u16*)(ws + 104 * MB);      // 104-136
    u16* WbV = (u16*)(ws + 136 * MB);      // 136-168
    u16* Vt  = WbQ;                        // weights dead after QKV GEMM
    u16* Ab  = WbK;
    u16* WbO = WbV;
    float* P01 = (float*)(ws);             // 0-64: split-K partials (xb..Vb dead)

    cvt_bf16<<<X8 / 256, 256, 0, stream>>>(x, xb, X8);
    cvt_bf16<<<W8 / 256, 256, 0, stream>>>(Wq, WbQ, W8);
    cvt_bf16<<<W8 / 256, 256, 0, stream>>>(Wk, WbK, W8);
    cvt_bf16<<<W8 / 256, 256, 0, stream>>>(Wv, WbV, W8);
    rope_table_k<<<(cB * cS * 64) / 256, 256, 0, stream>>>(pos, cosT, sinT);

    gemm_bt<0><<<dim3(16, 96), 256, 0, stream>>>(
        xb, WbQ, WbK, WbV, bq, bk, bv, Qb, Kb, Vb, cHID);

    rope_apply<<<(2 * R8) / 256, 256, 0, stream>>>(Qb, Kb, cosT, sinT);
    transpose_v<<<dim3(cS / 32, cHD / 32, cB * cNH), 256, 0, stream>>>(Vb, Vt);
    attn_kernel<<<dim3(cS / 128, cB * cNH), 256, 0, stream>>>(Qb, Kb, Vt, Ab);

    cvt_bf16<<<W8 / 256, 256, 0, stream>>>(Wo, WbO, W8);
    gemm_bt<2><<<dim3(16, 32, 2), 256, 0, stream>>>(
        Ab, WbO, WbO, WbO, nullptr, nullptr, nullptr, P01, P01, P01, cHID / 2);
    combine_bias<<<(cM * cHID / 4) / 256, 256, 0, stream>>>(P01, bo, out);
  } else {
    // -------- fallback serial path (97 MiB) --------
    u16* xb = (u16*)(ws);                 // 0-16, later Vt
    u16* Wb = (u16*)(ws + 16 * MB);       // 16-48
    u16* Qb = (u16*)(ws + 48 * MB);       // 48-64
    u16* Kb = (u16*)(ws + 64 * MB);       // 64-80
    u16* Vb = (u16*)(ws + 80 * MB);       // 80-96, later attn out
    u16* Vt = xb;
    u16* Ab = Vb;
    float* cosT = (float*)(ws + 96 * MB);
    float* sinT = cosT + cB * cS * 64;

    cvt_bf16<<<X8 / 256, 256, 0, stream>>>(x, xb, X8);
    cvt_bf16<<<W8 / 256, 256, 0, stream>>>(Wq, Wb, W8);
    gemm_bt<0><<<dim3(16, 32), 256, 0, stream>>>(
        xb, Wb, Wb, Wb, bq, bq, bq, Qb, Qb, Qb, cHID);
    cvt_bf16<<<W8 / 256, 256, 0, stream>>>(Wk, Wb, W8);
    gemm_bt<0><<<dim3(16, 32), 256, 0, stream>>>(
        xb, Wb, Wb, Wb, bk, bk, bk, Kb, Kb, Kb, cHID);
    cvt_bf16<<<W8 / 256, 256, 0, stream>>>(Wv, Wb, W8);
    gemm_bt<0><<<dim3(16, 32), 256, 0, stream>>>(
        xb, Wb, Wb, Wb, bv, bv, bv, Vb, Vb, Vb, cHID);

    rope_table_k<<<(cB * cS * 64) / 256, 256, 0, stream>>>(pos, cosT, sinT);
    rope_apply<<<(2 * R8) / 256, 256, 0, stream>>>(Qb, Kb, cosT, sinT);
    transpose_v<<<dim3(cS / 32, cHD / 32, cB * cNH), 256, 0, stream>>>(Vb, Vt);
    attn_kernel<<<dim3(cS / 128, cB * cNH), 256, 0, stream>>>(Qb, Kb, Vt, Ab);

    cvt_bf16<<<W8 / 256, 256, 0, stream>>>(Wo, Wb, W8);
    gemm_bt<1><<<dim3(16, 32), 256, 0, stream>>>(
        Ab, Wb, Wb, Wb, bo, bo, bo, out, out, out, cHID);
  }
}